// Round 1
// 420.638 us; speedup vs baseline: 1.0016x; 1.0016x over previous
//
#include <hip/hip_runtime.h>

// R7: memory-granularity round (TW 8 -> 16, NT 256 -> 512).
//  Theory: kernel portion (~99us of the 421; the rest is harness re-poison
//  fills) runs at ~2.7 TB/s effective vs 6.3 achievable. With TW=8 every
//  (c,d) pair contributes only 32B contiguous -> each wave load = 32
//  scattered 32B transactions, <=half of each 64B line used unless XCD
//  siblings hit L2 in time (footprint 2x oversubscribes the 4MiB L2).
//  Fix: TW=16 makes every (c,d) segment a full, aligned 64B (4 lanes x
//  float4), halving transactions and killing intra-line waste. Per-wave
//  compute structure (MFMA projections, softmax, Abar/Obar) is unchanged:
//  each wave still owns 64 rows = 2 sites. Occupancy preserved at
//  16 waves/CU (2 blocks x 8 waves, LDS 78,080B, launch_bounds(512,4)).
// Math: out = Xbar + f*(bo + Wo*(V*Abar)), Abar = mean_j softmax_i(K^T Q).
// LDS = 65536 + 8192 + 2048 + 2304 = 78,080 B -> 2 blocks/CU.

namespace {
constexpr int kB = 8, kC = 64, kD = 32, kH = 64, kW = 64, kS = 32;
constexpr int kHW = kH * kW;
constexpr int TW = 16, NT = 512;

typedef unsigned short u16t;
typedef unsigned int u32t;
typedef __attribute__((ext_vector_type(8))) short bf16x8;
typedef __attribute__((ext_vector_type(4))) float f32x4;

#if defined(__has_builtin)
#if __has_builtin(__builtin_amdgcn_cvt_pk_bf16_f32)
#define HAS_CVT_PK_BF16 1
#endif
#endif

__device__ __forceinline__ u32t pack2(float lo, float hi) {
#ifdef HAS_CVT_PK_BF16
    typedef __attribute__((ext_vector_type(2))) __bf16 v2bf;
    union { v2bf v; u32t u; } cv;
    cv.v = __builtin_amdgcn_cvt_pk_bf16_f32(lo, hi);
    return cv.u;
#else
    union { u32t i; float f; } a, b;
    a.f = lo; b.f = hi;
    u32t ra = a.i + 0x7FFFu + ((a.i >> 16) & 1u);
    u32t rb = b.i + 0x7FFFu + ((b.i >> 16) & 1u);
    return (ra >> 16) | (rb & 0xFFFF0000u);
#endif
}
__device__ __forceinline__ bf16x8 pack8(const float4 f0, const float4 f1) {
    union { bf16x8 v; u32t u[4]; } r;
    r.u[0] = pack2(f0.x, f0.y); r.u[1] = pack2(f0.z, f0.w);
    r.u[2] = pack2(f1.x, f1.y); r.u[3] = pack2(f1.z, f1.w);
    return r.v;
}
// select bf16 half of a packed pair as f32
__device__ __forceinline__ float bsel(u32t q, int odd) {
    union { u32t i; float f; } v;
    v.i = odd ? (q & 0xFFFF0000u) : (q << 16);
    return v.f;
}
} // namespace

__global__ __launch_bounds__(NT, 4) void attn_fused(
    const float* __restrict__ x,
    const float* __restrict__ Wk, const float* __restrict__ bk,
    const float* __restrict__ Wq, const float* __restrict__ bq,
    const float* __restrict__ Wv, const float* __restrict__ bv,
    const float* __restrict__ Wo, const float* __restrict__ bo,
    const float* __restrict__ factor,
    float* __restrict__ out)
{
    // KQX row (w*32+d) (0..511): 64 ushorts; 16B granule XOR-swizzled by (d&7).
    __shared__ __align__(16) u16t KQX[512 * 64];   // 65,536 B
    __shared__ u32t XbP[4 * 512];                  //  8,192 B : [dv][w][cp], bf16 pair (c even|odd)
    __shared__ float AbarS[16 * kD];               //  2,048 B : [wp][i]
    __shared__ __align__(16) float ObarS[16 * 36]; //  2,304 B : [wp][s] pad 36

    const int t = threadIdx.x;
    const int lane = t & 63;
    const int wv = t >> 6;        // 0..7
    const int l15 = lane & 15;
    const int quad = lane >> 4;

    // block swizzle: 4 w-tile siblings of one (b,h) row -> same XCD.
    const int blk = blockIdx.x;                      // 0..2047
    const int bh = (blk & 7) | ((blk >> 5) << 3);    // 0..511
    const int wt = (blk >> 3) & 3;
    const int b = bh >> 6, h = bh & 63, w0 = wt * TW;

    // ---- stage X: 16 loads forced in flight, then consume ----
    // thread map: w4 = t&3 (float4 within 16 w's -> 64B coalesced per (c,d)),
    //             cp = (t>>2)&31 (c-pair), dv = t>>7; d = dv + it*4.
    {
        const float* xb = x + (size_t)(b * kC * kD) * kHW + h * kW + w0;
        const int w4 = t & 3, cp = (t >> 2) & 31, dv = t >> 7;
        const float* p0 = xb + (size_t)((cp * 2) * kD + dv) * kHW + w4 * 4;
        const float* p1 = p0 + (size_t)kD * kHW;
        float4 fa[8], fb[8];
        #pragma unroll
        for (int it = 0; it < 8; ++it) {
            fa[it] = *(const float4*)(p0 + (size_t)(it * 4) * kHW);
            fb[it] = *(const float4*)(p1 + (size_t)(it * 4) * kHW);
        }
        __builtin_amdgcn_sched_barrier(0);   // all 16 loads issued before use

        // Xbar partials over this thread's 8 d's (f32), packed bf16 to LDS
        float4 sA = fa[0], sB = fb[0];
        #pragma unroll
        for (int it = 1; it < 8; ++it) {
            sA.x += fa[it].x; sA.y += fa[it].y; sA.z += fa[it].z; sA.w += fa[it].w;
            sB.x += fb[it].x; sB.y += fb[it].y; sB.z += fb[it].z; sB.w += fb[it].w;
        }
        XbP[dv * 512 + w4 * 128 + 0 * 32 + cp] = pack2(sA.x, sB.x);
        XbP[dv * 512 + w4 * 128 + 1 * 32 + cp] = pack2(sA.y, sB.y);
        XbP[dv * 512 + w4 * 128 + 2 * 32 + cp] = pack2(sA.z, sB.z);
        XbP[dv * 512 + w4 * 128 + 3 * 32 + cp] = pack2(sA.w, sB.w);

        // pack + swizzled staging writes; row = (w4*4+e)*32 + d
        u32t* dst = (u32t*)KQX;
        const int gsw = cp >> 2, gin = cp & 3;
        #pragma unroll
        for (int it = 0; it < 8; ++it) {
            int d = dv + it * 4;
            int sw = d & 7;
            int pg = (gsw ^ sw) * 4 + gin;
            int r0 = w4 * 128 + d;
            dst[(r0 + 0 * 32) * 32 + pg] = pack2(fa[it].x, fb[it].x);
            dst[(r0 + 1 * 32) * 32 + pg] = pack2(fa[it].y, fb[it].y);
            dst[(r0 + 2 * 32) * 32 + pg] = pack2(fa[it].z, fb[it].z);
            dst[(r0 + 3 * 32) * 32 + pg] = pack2(fa[it].w, fb[it].w);
        }
    }

    // ---- prefetch + pack weight A-frags and biases (overlaps barrier) ----
    bf16x8 Af[3][2][2];
    float4 bias4[3][2];
    {
        const float* Wp[3] = {Wk, Wq, Wv};
        const float* bp[3] = {bk, bq, bv};
        #pragma unroll
        for (int p = 0; p < 3; ++p) {
            #pragma unroll
            for (int m0 = 0; m0 < 2; ++m0) {
                #pragma unroll
                for (int ks = 0; ks < 2; ++ks) {
                    const float* src = Wp[p] + (m0 * 16 + l15) * kC + ks * 32 + quad * 8;
                    Af[p][m0][ks] = pack8(*(const float4*)src, *(const float4*)(src + 4));
                }
                bias4[p][m0] = *(const float4*)(bp[p] + m0 * 16 + quad * 4);
            }
        }
    }
    __syncthreads();

    // ---- load B-frags for this wave's 64 n-rows (swizzled granules) ----
    bf16x8 Bf[4][2];
    #pragma unroll
    for (int nt = 0; nt < 4; ++nt) {
        int row = wv * 64 + nt * 16 + l15;
        int sw = l15 & 7;
        #pragma unroll
        for (int ks = 0; ks < 2; ++ks)
            Bf[nt][ks] = *(const bf16x8*)&KQX[row * 64 + ((ks * 4 + quad) ^ sw) * 8];
    }

    // ---- projections via MFMA; K,Q -> own LDS rows (bf16); V -> f32 regs ----
    f32x4 Vf[2][4];
    #pragma unroll
    for (int p = 0; p < 3; ++p) {
        #pragma unroll
        for (int m0 = 0; m0 < 2; ++m0) {
            #pragma unroll
            for (int nt = 0; nt < 4; ++nt) {
                f32x4 acc = {0.f, 0.f, 0.f, 0.f};
                acc = __builtin_amdgcn_mfma_f32_16x16x32_bf16(Af[p][m0][0], Bf[nt][0], acc, 0, 0, 0);
                acc = __builtin_amdgcn_mfma_f32_16x16x32_bf16(Af[p][m0][1], Bf[nt][1], acc, 0, 0, 0);
                if (p < 2) {
                    u32t lo = pack2(acc[0] + bias4[p][m0].x, acc[1] + bias4[p][m0].y);
                    u32t hi = pack2(acc[2] + bias4[p][m0].z, acc[3] + bias4[p][m0].w);
                    int row = wv * 64 + nt * 16 + l15;
                    int g = (p == 0 ? 0 : 4) + m0 * 2 + (quad >> 1);
                    uint2 pr; pr.x = lo; pr.y = hi;
                    *(uint2*)&KQX[row * 64 + ((g ^ (l15 & 7)) * 8) + (quad & 1) * 4] = pr;
                } else {
                    Vf[m0][nt][0] = acc[0] + bias4[2][m0].x;
                    Vf[m0][nt][1] = acc[1] + bias4[2][m0].y;
                    Vf[m0][nt][2] = acc[2] + bias4[2][m0].z;
                    Vf[m0][nt][3] = acc[3] + bias4[2][m0].w;
                }
            }
        }
    }
    // no barrier: scores read only this wave's own rows (in-order DS pipe).

    // ---- scores + softmax (no max-sub) + Abar + Obar, 2 sites/wave ----
    {
        const float kScaleLog2e = 0.25501700249569946f;  // (1/sqrt(32))*log2(e)
        #pragma unroll
        for (int si = 0; si < 2; ++si) {
            int wp = wv * 2 + si;                  // site (w') 0..15
            bf16x8 Ka[2], Qb[2];
            #pragma unroll
            for (int m0 = 0; m0 < 2; ++m0) {
                int rr = wp * 32 + m0 * 16 + l15;
                Ka[m0] = *(const bf16x8*)&KQX[rr * 64 + ((quad ^ (l15 & 7)) * 8)];
            }
            #pragma unroll
            for (int n0 = 0; n0 < 2; ++n0) {
                int rr = wp * 32 + n0 * 16 + l15;
                Qb[n0] = *(const bf16x8*)&KQX[rr * 64 + (((4 + quad) ^ (l15 & 7)) * 8)];
            }
            f32x4 sc[2][2];
            #pragma unroll
            for (int m0 = 0; m0 < 2; ++m0)
                #pragma unroll
                for (int n0 = 0; n0 < 2; ++n0) {
                    f32x4 z = {0.f, 0.f, 0.f, 0.f};
                    sc[m0][n0] = __builtin_amdgcn_mfma_f32_16x16x32_bf16(Ka[m0], Qb[n0], z, 0, 0, 0);
                }
            // softmax over i per column j = n0*16 + l15
            #pragma unroll
            for (int n0 = 0; n0 < 2; ++n0) {
                float sum = 0.f;
                #pragma unroll
                for (int m0 = 0; m0 < 2; ++m0)
                    #pragma unroll
                    for (int r2 = 0; r2 < 4; ++r2) {
                        float e = exp2f(sc[m0][n0][r2] * kScaleLog2e);
                        sc[m0][n0][r2] = e; sum += e;
                    }
                sum += __shfl_xor(sum, 16);
                sum += __shfl_xor(sum, 32);
                float inv = __builtin_amdgcn_rcpf(sum);
                #pragma unroll
                for (int m0 = 0; m0 < 2; ++m0)
                    #pragma unroll
                    for (int r2 = 0; r2 < 4; ++r2) sc[m0][n0][r2] *= inv;
            }
            // Abar[i] = (1/32) * sum_j a[i,j]  -> AbarS[wp][i]
            #pragma unroll
            for (int m0 = 0; m0 < 2; ++m0)
                #pragma unroll
                for (int r2 = 0; r2 < 4; ++r2) {
                    float v2 = sc[m0][0][r2] + sc[m0][1][r2];
                    v2 += __shfl_xor(v2, 1);
                    v2 += __shfl_xor(v2, 2);
                    v2 += __shfl_xor(v2, 4);
                    v2 += __shfl_xor(v2, 8);
                    if (l15 == 0)
                        AbarS[wp * kD + m0 * 16 + quad * 4 + r2] = v2 * (1.0f / kD);
                }
            // Obar[s] = sum_d V[s,d]*Abar[d] (V f32 C-frags; d = g*16+l15)
            {
                float ab0 = AbarS[wp * kD + l15];
                float ab1 = AbarS[wp * kD + 16 + l15];
                #pragma unroll
                for (int m0 = 0; m0 < 2; ++m0)
                    #pragma unroll
                    for (int r2 = 0; r2 < 4; ++r2) {
                        float v = Vf[m0][2 * si + 0][r2] * ab0
                                + Vf[m0][2 * si + 1][r2] * ab1;
                        v += __shfl_xor(v, 1);
                        v += __shfl_xor(v, 2);
                        v += __shfl_xor(v, 4);
                        v += __shfl_xor(v, 8);
                        if (l15 == 0)
                            ObarS[wp * 36 + m0 * 16 + quad * 4 + r2] = v;
                    }
            }
        }
    }
    __syncthreads();

    // ---- final: out[c] = Xbar + f*(bo + Wo*Obar), coalesced over w ----
    {
        const float fac = factor[0];
        const int wp = t & 15, cl = t >> 4;   // cl 0..31
        const float4* obp = (const float4*)&ObarS[wp * 36];
        float4 ob4[8];
        #pragma unroll
        for (int s4 = 0; s4 < 8; ++s4) ob4[s4] = obp[s4];
        const int odd = cl & 1;
        #pragma unroll
        for (int half = 0; half < 2; ++half) {
            int c = cl + half * 32;
            int cpi = (cl >> 1) + half * 16;
            float xbar = bsel(XbP[0 * 512 + wp * 32 + cpi], odd)
                       + bsel(XbP[1 * 512 + wp * 32 + cpi], odd)
                       + bsel(XbP[2 * 512 + wp * 32 + cpi], odd)
                       + bsel(XbP[3 * 512 + wp * 32 + cpi], odd);
            xbar *= (1.0f / kD);
            const float4* wrow = (const float4*)(Wo + c * kS);
            float acc = 0.f;
            #pragma unroll
            for (int s4 = 0; s4 < 8; ++s4) {
                float4 w4 = wrow[s4];
                acc += w4.x * ob4[s4].x;
                acc += w4.y * ob4[s4].y;
                acc += w4.z * ob4[s4].z;
                acc += w4.w * ob4[s4].w;
            }
            out[((b * kC + c) * kH + h) * kW + w0 + wp] =
                xbar + fac * (bo[c] + acc);
        }
    }
}

extern "C" void kernel_launch(void* const* d_in, const int* in_sizes, int n_in,
                              void* d_out, int out_size, void* d_ws, size_t ws_size,
                              hipStream_t stream) {
    const float* x      = (const float*)d_in[0];
    const float* Wk     = (const float*)d_in[1];
    const float* bk     = (const float*)d_in[2];
    const float* Wq     = (const float*)d_in[3];
    const float* bq     = (const float*)d_in[4];
    const float* Wv     = (const float*)d_in[5];
    const float* bv     = (const float*)d_in[6];
    const float* Wo     = (const float*)d_in[7];
    const float* bo     = (const float*)d_in[8];
    const float* factor = (const float*)d_in[9];
    float* out = (float*)d_out;

    dim3 grid(kB * kH * (kW / TW));  // 2048 blocks
    attn_fused<<<grid, NT, 0, stream>>>(x, Wk, bk, Wq, bq, Wv, bv, Wo, bo, factor, out);
}

// Round 2
// 419.964 us; speedup vs baseline: 1.0032x; 1.0016x over previous
//
#include <hip/hip_runtime.h>

// R8: DRAM row-locality round (pure block-swizzle change + XbP LDS fix).
//  R7 post-mortem: TW 8->16 was exactly neutral -> L2 sibling line-merge
//  already worked; DRAM sees 128B fetches @16KiB stride either way, and
//  kernel (~99us of the 421; rest is harness poison fills) runs at ~2.7
//  of 6.6 TB/s -> row-buffer thrash. Fix: XCD k owns h-slab [8k,8k+8)
//  so each XCD's L2 miss stream requests 8 CONSECUTIVE 256B rows = 2KiB
//  contiguous per (c,d) plane (16 back-to-back 128B lines -> HBM row
//  hits), instead of h strided by 8. w-tile siblings (line-sharing) and
//  b in {0,1} stay co-resident per XCD. Per-wave compute unchanged.
//  Also: XbP epilogue reads were 16-way bank-conflicted (bank=cpi only);
//  XOR in-row index with w on both sides -> 2-way (free), writes still
//  4-way (unchanged).
// Math: out = Xbar + f*(bo + Wo*(V*Abar)), Abar = mean_j softmax_i(K^T Q).
// LDS = 65536 + 8192 + 2048 + 2304 = 78,080 B -> 2 blocks/CU.

namespace {
constexpr int kB = 8, kC = 64, kD = 32, kH = 64, kW = 64, kS = 32;
constexpr int kHW = kH * kW;
constexpr int TW = 16, NT = 512;

typedef unsigned short u16t;
typedef unsigned int u32t;
typedef __attribute__((ext_vector_type(8))) short bf16x8;
typedef __attribute__((ext_vector_type(4))) float f32x4;

#if defined(__has_builtin)
#if __has_builtin(__builtin_amdgcn_cvt_pk_bf16_f32)
#define HAS_CVT_PK_BF16 1
#endif
#endif

__device__ __forceinline__ u32t pack2(float lo, float hi) {
#ifdef HAS_CVT_PK_BF16
    typedef __attribute__((ext_vector_type(2))) __bf16 v2bf;
    union { v2bf v; u32t u; } cv;
    cv.v = __builtin_amdgcn_cvt_pk_bf16_f32(lo, hi);
    return cv.u;
#else
    union { u32t i; float f; } a, b;
    a.f = lo; b.f = hi;
    u32t ra = a.i + 0x7FFFu + ((a.i >> 16) & 1u);
    u32t rb = b.i + 0x7FFFu + ((b.i >> 16) & 1u);
    return (ra >> 16) | (rb & 0xFFFF0000u);
#endif
}
__device__ __forceinline__ bf16x8 pack8(const float4 f0, const float4 f1) {
    union { bf16x8 v; u32t u[4]; } r;
    r.u[0] = pack2(f0.x, f0.y); r.u[1] = pack2(f0.z, f0.w);
    r.u[2] = pack2(f1.x, f1.y); r.u[3] = pack2(f1.z, f1.w);
    return r.v;
}
// select bf16 half of a packed pair as f32
__device__ __forceinline__ float bsel(u32t q, int odd) {
    union { u32t i; float f; } v;
    v.i = odd ? (q & 0xFFFF0000u) : (q << 16);
    return v.f;
}
} // namespace

__global__ __launch_bounds__(NT, 4) void attn_fused(
    const float* __restrict__ x,
    const float* __restrict__ Wk, const float* __restrict__ bk,
    const float* __restrict__ Wq, const float* __restrict__ bq,
    const float* __restrict__ Wv, const float* __restrict__ bv,
    const float* __restrict__ Wo, const float* __restrict__ bo,
    const float* __restrict__ factor,
    float* __restrict__ out)
{
    // KQX row (w*32+d) (0..511): 64 ushorts; 16B granule XOR-swizzled by (d&7).
    __shared__ __align__(16) u16t KQX[512 * 64];   // 65,536 B
    __shared__ u32t XbP[4 * 512];                  //  8,192 B : [dv][w][cp^w], bf16 pair (c even|odd)
    __shared__ float AbarS[16 * kD];               //  2,048 B : [wp][i]
    __shared__ __align__(16) float ObarS[16 * 36]; //  2,304 B : [wp][s] pad 36

    const int t = threadIdx.x;
    const int lane = t & 63;
    const int wv = t >> 6;        // 0..7
    const int l15 = lane & 15;
    const int quad = lane >> 4;

    // block swizzle: XCD k (= blk%8 round-robin) owns h-slab [8k, 8k+8).
    // Within an XCD, dispatch order = (b major, wt, hl minor) so the ~64
    // resident blocks cover b in {0,1} x all 4 wt x 8 consecutive h ->
    // per (c,d) plane the XCD requests a contiguous 2KiB (8 rows x 256B).
    const int blk = blockIdx.x;                  // 0..2047
    const int xcd = blk & 7;
    const int hl  = (blk >> 3) & 7;
    const int wt  = (blk >> 6) & 3;
    const int b   = blk >> 8;                    // 0..7
    const int h   = xcd * 8 + hl;
    const int w0  = wt * TW;

    // ---- stage X: 16 loads forced in flight, then consume ----
    // thread map: w4 = t&3 (float4 within 16 w's -> 64B coalesced per (c,d)),
    //             cp = (t>>2)&31 (c-pair), dv = t>>7; d = dv + it*4.
    {
        const float* xb = x + (size_t)(b * kC * kD) * kHW + h * kW + w0;
        const int w4 = t & 3, cp = (t >> 2) & 31, dv = t >> 7;
        const float* p0 = xb + (size_t)((cp * 2) * kD + dv) * kHW + w4 * 4;
        const float* p1 = p0 + (size_t)kD * kHW;
        float4 fa[8], fb[8];
        #pragma unroll
        for (int it = 0; it < 8; ++it) {
            fa[it] = *(const float4*)(p0 + (size_t)(it * 4) * kHW);
            fb[it] = *(const float4*)(p1 + (size_t)(it * 4) * kHW);
        }
        __builtin_amdgcn_sched_barrier(0);   // all 16 loads issued before use

        // Xbar partials over this thread's 8 d's (f32), packed bf16 to LDS
        float4 sA = fa[0], sB = fb[0];
        #pragma unroll
        for (int it = 1; it < 8; ++it) {
            sA.x += fa[it].x; sA.y += fa[it].y; sA.z += fa[it].z; sA.w += fa[it].w;
            sB.x += fb[it].x; sB.y += fb[it].y; sB.z += fb[it].z; sB.w += fb[it].w;
        }
        // in-row index XOR'd with w so epilogue reads spread across banks
        {
            const int wbase = dv * 512 + w4 * 128;
            XbP[wbase + 0 * 32 + (cp ^ (w4 * 4 + 0))] = pack2(sA.x, sB.x);
            XbP[wbase + 1 * 32 + (cp ^ (w4 * 4 + 1))] = pack2(sA.y, sB.y);
            XbP[wbase + 2 * 32 + (cp ^ (w4 * 4 + 2))] = pack2(sA.z, sB.z);
            XbP[wbase + 3 * 32 + (cp ^ (w4 * 4 + 3))] = pack2(sA.w, sB.w);
        }

        // pack + swizzled staging writes; row = (w4*4+e)*32 + d
        u32t* dst = (u32t*)KQX;
        const int gsw = cp >> 2, gin = cp & 3;
        #pragma unroll
        for (int it = 0; it < 8; ++it) {
            int d = dv + it * 4;
            int sw = d & 7;
            int pg = (gsw ^ sw) * 4 + gin;
            int r0 = w4 * 128 + d;
            dst[(r0 + 0 * 32) * 32 + pg] = pack2(fa[it].x, fb[it].x);
            dst[(r0 + 1 * 32) * 32 + pg] = pack2(fa[it].y, fb[it].y);
            dst[(r0 + 2 * 32) * 32 + pg] = pack2(fa[it].z, fb[it].z);
            dst[(r0 + 3 * 32) * 32 + pg] = pack2(fa[it].w, fb[it].w);
        }
    }

    // ---- prefetch + pack weight A-frags and biases (overlaps barrier) ----
    bf16x8 Af[3][2][2];
    float4 bias4[3][2];
    {
        const float* Wp[3] = {Wk, Wq, Wv};
        const float* bp[3] = {bk, bq, bv};
        #pragma unroll
        for (int p = 0; p < 3; ++p) {
            #pragma unroll
            for (int m0 = 0; m0 < 2; ++m0) {
                #pragma unroll
                for (int ks = 0; ks < 2; ++ks) {
                    const float* src = Wp[p] + (m0 * 16 + l15) * kC + ks * 32 + quad * 8;
                    Af[p][m0][ks] = pack8(*(const float4*)src, *(const float4*)(src + 4));
                }
                bias4[p][m0] = *(const float4*)(bp[p] + m0 * 16 + quad * 4);
            }
        }
    }
    __syncthreads();

    // ---- load B-frags for this wave's 64 n-rows (swizzled granules) ----
    bf16x8 Bf[4][2];
    #pragma unroll
    for (int nt = 0; nt < 4; ++nt) {
        int row = wv * 64 + nt * 16 + l15;
        int sw = l15 & 7;
        #pragma unroll
        for (int ks = 0; ks < 2; ++ks)
            Bf[nt][ks] = *(const bf16x8*)&KQX[row * 64 + ((ks * 4 + quad) ^ sw) * 8];
    }

    // ---- projections via MFMA; K,Q -> own LDS rows (bf16); V -> f32 regs ----
    f32x4 Vf[2][4];
    #pragma unroll
    for (int p = 0; p < 3; ++p) {
        #pragma unroll
        for (int m0 = 0; m0 < 2; ++m0) {
            #pragma unroll
            for (int nt = 0; nt < 4; ++nt) {
                f32x4 acc = {0.f, 0.f, 0.f, 0.f};
                acc = __builtin_amdgcn_mfma_f32_16x16x32_bf16(Af[p][m0][0], Bf[nt][0], acc, 0, 0, 0);
                acc = __builtin_amdgcn_mfma_f32_16x16x32_bf16(Af[p][m0][1], Bf[nt][1], acc, 0, 0, 0);
                if (p < 2) {
                    u32t lo = pack2(acc[0] + bias4[p][m0].x, acc[1] + bias4[p][m0].y);
                    u32t hi = pack2(acc[2] + bias4[p][m0].z, acc[3] + bias4[p][m0].w);
                    int row = wv * 64 + nt * 16 + l15;
                    int g = (p == 0 ? 0 : 4) + m0 * 2 + (quad >> 1);
                    uint2 pr; pr.x = lo; pr.y = hi;
                    *(uint2*)&KQX[row * 64 + ((g ^ (l15 & 7)) * 8) + (quad & 1) * 4] = pr;
                } else {
                    Vf[m0][nt][0] = acc[0] + bias4[2][m0].x;
                    Vf[m0][nt][1] = acc[1] + bias4[2][m0].y;
                    Vf[m0][nt][2] = acc[2] + bias4[2][m0].z;
                    Vf[m0][nt][3] = acc[3] + bias4[2][m0].w;
                }
            }
        }
    }
    // no barrier: scores read only this wave's own rows (in-order DS pipe).

    // ---- scores + softmax (no max-sub) + Abar + Obar, 2 sites/wave ----
    {
        const float kScaleLog2e = 0.25501700249569946f;  // (1/sqrt(32))*log2(e)
        #pragma unroll
        for (int si = 0; si < 2; ++si) {
            int wp = wv * 2 + si;                  // site (w') 0..15
            bf16x8 Ka[2], Qb[2];
            #pragma unroll
            for (int m0 = 0; m0 < 2; ++m0) {
                int rr = wp * 32 + m0 * 16 + l15;
                Ka[m0] = *(const bf16x8*)&KQX[rr * 64 + ((quad ^ (l15 & 7)) * 8)];
            }
            #pragma unroll
            for (int n0 = 0; n0 < 2; ++n0) {
                int rr = wp * 32 + n0 * 16 + l15;
                Qb[n0] = *(const bf16x8*)&KQX[rr * 64 + (((4 + quad) ^ (l15 & 7)) * 8)];
            }
            f32x4 sc[2][2];
            #pragma unroll
            for (int m0 = 0; m0 < 2; ++m0)
                #pragma unroll
                for (int n0 = 0; n0 < 2; ++n0) {
                    f32x4 z = {0.f, 0.f, 0.f, 0.f};
                    sc[m0][n0] = __builtin_amdgcn_mfma_f32_16x16x32_bf16(Ka[m0], Qb[n0], z, 0, 0, 0);
                }
            // softmax over i per column j = n0*16 + l15
            #pragma unroll
            for (int n0 = 0; n0 < 2; ++n0) {
                float sum = 0.f;
                #pragma unroll
                for (int m0 = 0; m0 < 2; ++m0)
                    #pragma unroll
                    for (int r2 = 0; r2 < 4; ++r2) {
                        float e = exp2f(sc[m0][n0][r2] * kScaleLog2e);
                        sc[m0][n0][r2] = e; sum += e;
                    }
                sum += __shfl_xor(sum, 16);
                sum += __shfl_xor(sum, 32);
                float inv = __builtin_amdgcn_rcpf(sum);
                #pragma unroll
                for (int m0 = 0; m0 < 2; ++m0)
                    #pragma unroll
                    for (int r2 = 0; r2 < 4; ++r2) sc[m0][n0][r2] *= inv;
            }
            // Abar[i] = (1/32) * sum_j a[i,j]  -> AbarS[wp][i]
            #pragma unroll
            for (int m0 = 0; m0 < 2; ++m0)
                #pragma unroll
                for (int r2 = 0; r2 < 4; ++r2) {
                    float v2 = sc[m0][0][r2] + sc[m0][1][r2];
                    v2 += __shfl_xor(v2, 1);
                    v2 += __shfl_xor(v2, 2);
                    v2 += __shfl_xor(v2, 4);
                    v2 += __shfl_xor(v2, 8);
                    if (l15 == 0)
                        AbarS[wp * kD + m0 * 16 + quad * 4 + r2] = v2 * (1.0f / kD);
                }
            // Obar[s] = sum_d V[s,d]*Abar[d] (V f32 C-frags; d = g*16+l15)
            {
                float ab0 = AbarS[wp * kD + l15];
                float ab1 = AbarS[wp * kD + 16 + l15];
                #pragma unroll
                for (int m0 = 0; m0 < 2; ++m0)
                    #pragma unroll
                    for (int r2 = 0; r2 < 4; ++r2) {
                        float v = Vf[m0][2 * si + 0][r2] * ab0
                                + Vf[m0][2 * si + 1][r2] * ab1;
                        v += __shfl_xor(v, 1);
                        v += __shfl_xor(v, 2);
                        v += __shfl_xor(v, 4);
                        v += __shfl_xor(v, 8);
                        if (l15 == 0)
                            ObarS[wp * 36 + m0 * 16 + quad * 4 + r2] = v;
                    }
            }
        }
    }
    __syncthreads();

    // ---- final: out[c] = Xbar + f*(bo + Wo*Obar), coalesced over w ----
    {
        const float fac = factor[0];
        const int wp = t & 15, cl = t >> 4;   // cl 0..31
        const float4* obp = (const float4*)&ObarS[wp * 36];
        float4 ob4[8];
        #pragma unroll
        for (int s4 = 0; s4 < 8; ++s4) ob4[s4] = obp[s4];
        const int odd = cl & 1;
        #pragma unroll
        for (int half = 0; half < 2; ++half) {
            int c = cl + half * 32;
            int cpi = (cl >> 1) + half * 16;
            const int xi = wp * 32 + (cpi ^ wp);
            float xbar = bsel(XbP[0 * 512 + xi], odd)
                       + bsel(XbP[1 * 512 + xi], odd)
                       + bsel(XbP[2 * 512 + xi], odd)
                       + bsel(XbP[3 * 512 + xi], odd);
            xbar *= (1.0f / kD);
            const float4* wrow = (const float4*)(Wo + c * kS);
            float acc = 0.f;
            #pragma unroll
            for (int s4 = 0; s4 < 8; ++s4) {
                float4 w4 = wrow[s4];
                acc += w4.x * ob4[s4].x;
                acc += w4.y * ob4[s4].y;
                acc += w4.z * ob4[s4].z;
                acc += w4.w * ob4[s4].w;
            }
            out[((b * kC + c) * kH + h) * kW + w0 + wp] =
                xbar + fac * (bo[c] + acc);
        }
    }
}

extern "C" void kernel_launch(void* const* d_in, const int* in_sizes, int n_in,
                              void* d_out, int out_size, void* d_ws, size_t ws_size,
                              hipStream_t stream) {
    const float* x      = (const float*)d_in[0];
    const float* Wk     = (const float*)d_in[1];
    const float* bk     = (const float*)d_in[2];
    const float* Wq     = (const float*)d_in[3];
    const float* bq     = (const float*)d_in[4];
    const float* Wv     = (const float*)d_in[5];
    const float* bv     = (const float*)d_in[6];
    const float* Wo     = (const float*)d_in[7];
    const float* bo     = (const float*)d_in[8];
    const float* factor = (const float*)d_in[9];
    float* out = (float*)d_out;

    dim3 grid(kB * kH * (kW / TW));  // 2048 blocks
    attn_fused<<<grid, NT, 0, stream>>>(x, Wk, bk, Wq, bq, Wv, bv, Wo, bo, factor, out);
}

// Round 5
// 419.535 us; speedup vs baseline: 1.0042x; 1.0010x over previous
//
#include <hip/hip_runtime.h>

// R9c: latency-exposure round (R9b compile fix: float4 can't be a "v" asm
//  operand on gfx950 -> consume one scalar component per load dest; the
//  remaining components are used after the asm, so the RA must keep all
//  16 float4 tuples live across it -> all 16 loads in flight, one wait).
//  R8 post-mortem: kernel is NOT BW-bound (800 GB/s = 10% peak, FETCH 136MB
//  < compulsory); MfmaUtil 3%, VALU 25%, occupancy 35% -> latency-bound.
//  VGPR_Count=64 == sizeof(fa+fb): RA recycles load dests -> 16 staging
//  loads run in register-starved batches -> multiple exposed ~900cy HBM
//  latencies per wave. Fixes:
//   (1) asm-liveness pin (above), under proven-good launch_bounds(512,4).
//   (2) staging-write bank fix: row stride 128B -> bank = granule col;
//       XOR granule with (w4<<1) (uniform per read instr -> reads stay
//       conflict-free; writes 4-way -> 2-way = free).
//   (3) dispatch mapping: R1 verbatim (best measured; R8's h-slab
//       experiment regressed 159->178 profiled).
//   (4) XbP epilogue reads: in-row index XOR'd with w on both sides
//       (was 16-way bank conflict, now 2-way = free).
// Math: out = Xbar + f*(bo + Wo*(V*Abar)), Abar = mean_j softmax_i(K^T Q).
// LDS = 65536 + 8192 + 2048 + 2304 = 78,080 B -> 2 blocks/CU.

namespace {
constexpr int kB = 8, kC = 64, kD = 32, kH = 64, kW = 64, kS = 32;
constexpr int kHW = kH * kW;
constexpr int TW = 16, NT = 512;

typedef unsigned short u16t;
typedef unsigned int u32t;
typedef __attribute__((ext_vector_type(8))) short bf16x8;
typedef __attribute__((ext_vector_type(4))) float f32x4;

#if defined(__has_builtin)
#if __has_builtin(__builtin_amdgcn_cvt_pk_bf16_f32)
#define HAS_CVT_PK_BF16 1
#endif
#endif

__device__ __forceinline__ u32t pack2(float lo, float hi) {
#ifdef HAS_CVT_PK_BF16
    typedef __attribute__((ext_vector_type(2))) __bf16 v2bf;
    union { v2bf v; u32t u; } cv;
    cv.v = __builtin_amdgcn_cvt_pk_bf16_f32(lo, hi);
    return cv.u;
#else
    union { u32t i; float f; } a, b;
    a.f = lo; b.f = hi;
    u32t ra = a.i + 0x7FFFu + ((a.i >> 16) & 1u);
    u32t rb = b.i + 0x7FFFu + ((b.i >> 16) & 1u);
    return (ra >> 16) | (rb & 0xFFFF0000u);
#endif
}
__device__ __forceinline__ bf16x8 pack8(const float4 f0, const float4 f1) {
    union { bf16x8 v; u32t u[4]; } r;
    r.u[0] = pack2(f0.x, f0.y); r.u[1] = pack2(f0.z, f0.w);
    r.u[2] = pack2(f1.x, f1.y); r.u[3] = pack2(f1.z, f1.w);
    return r.v;
}
// select bf16 half of a packed pair as f32
__device__ __forceinline__ float bsel(u32t q, int odd) {
    union { u32t i; float f; } v;
    v.i = odd ? (q & 0xFFFF0000u) : (q << 16);
    return v.f;
}
} // namespace

__global__ __launch_bounds__(NT, 4) void attn_fused(
    const float* __restrict__ x,
    const float* __restrict__ Wk, const float* __restrict__ bk,
    const float* __restrict__ Wq, const float* __restrict__ bq,
    const float* __restrict__ Wv, const float* __restrict__ bv,
    const float* __restrict__ Wo, const float* __restrict__ bo,
    const float* __restrict__ factor,
    float* __restrict__ out)
{
    // KQX row (w*32+d) (0..511): 64 ushorts; 16B granule index XOR'd with
    // (row&7) ^ ((row>>7)<<1)  [= (d&7) ^ ((w>>2)<<1)].
    __shared__ __align__(16) u16t KQX[512 * 64];   // 65,536 B
    __shared__ u32t XbP[4 * 512];                  //  8,192 B : [dv][w][cp^w], bf16 pair (c even|odd)
    __shared__ float AbarS[16 * kD];               //  2,048 B : [wp][i]
    __shared__ __align__(16) float ObarS[16 * 36]; //  2,304 B : [wp][s] pad 36

    const int t = threadIdx.x;
    const int lane = t & 63;
    const int wv = t >> 6;        // 0..7
    const int l15 = lane & 15;
    const int quad = lane >> 4;

    // dispatch mapping: R1 verbatim (best measured). 8 (b,h)-siblings of
    // one w-tile round-robin the XCDs; the 4 w-tile siblings of one (b,h)
    // are 8/16/24 dispatch slots apart (co-resident, L2 line merge).
    const int blk = blockIdx.x;                      // 0..2047
    const int bh = (blk & 7) | ((blk >> 5) << 3);    // 0..511
    const int wt = (blk >> 3) & 3;
    const int b = bh >> 6, h = bh & 63, w0 = wt * TW;

    // ---- stage X: 16 loads forced in flight, then consume ----
    // thread map: w4 = t&3 (float4 within 16 w's -> 64B coalesced per (c,d)),
    //             cp = (t>>2)&31 (c-pair), dv = t>>7; d = dv + it*4.
    {
        const float* xb = x + (size_t)(b * kC * kD) * kHW + h * kW + w0;
        const int w4 = t & 3, cp = (t >> 2) & 31, dv = t >> 7;
        const float* p0 = xb + (size_t)((cp * 2) * kD + dv) * kHW + w4 * 4;
        const float* p1 = p0 + (size_t)kD * kHW;
        float4 fa[8], fb[8];
        #pragma unroll
        for (int it = 0; it < 8; ++it) {
            fa[it] = *(const float4*)(p0 + (size_t)(it * 4) * kHW);
            fb[it] = *(const float4*)(p1 + (size_t)(it * 4) * kHW);
        }
        __builtin_amdgcn_sched_barrier(0);   // no motion across this point
        // Liveness pin: read one scalar of each load dest here; the other
        // components are consumed after, so the RA must keep all 16 float4
        // tuples live across this asm -> 16 loads in flight, single wait.
        asm volatile("" ::
            "v"(fa[0].x), "v"(fa[1].x), "v"(fa[2].x), "v"(fa[3].x),
            "v"(fa[4].x), "v"(fa[5].x), "v"(fa[6].x), "v"(fa[7].x),
            "v"(fb[0].x), "v"(fb[1].x), "v"(fb[2].x), "v"(fb[3].x),
            "v"(fb[4].x), "v"(fb[5].x), "v"(fb[6].x), "v"(fb[7].x));

        // Xbar partials over this thread's 8 d's (f32), packed bf16 to LDS
        float4 sA = fa[0], sB = fb[0];
        #pragma unroll
        for (int it = 1; it < 8; ++it) {
            sA.x += fa[it].x; sA.y += fa[it].y; sA.z += fa[it].z; sA.w += fa[it].w;
            sB.x += fb[it].x; sB.y += fb[it].y; sB.z += fb[it].z; sB.w += fb[it].w;
        }
        // in-row index XOR'd with w so epilogue reads spread across banks
        {
            const int wbase = dv * 512 + w4 * 128;
            XbP[wbase + 0 * 32 + (cp ^ (w4 * 4 + 0))] = pack2(sA.x, sB.x);
            XbP[wbase + 1 * 32 + (cp ^ (w4 * 4 + 1))] = pack2(sA.y, sB.y);
            XbP[wbase + 2 * 32 + (cp ^ (w4 * 4 + 2))] = pack2(sA.z, sB.z);
            XbP[wbase + 3 * 32 + (cp ^ (w4 * 4 + 3))] = pack2(sA.w, sB.w);
        }

        // pack + swizzled staging writes; row = (w4*4+e)*32 + d.
        // granule = (gsw ^ (d&7) ^ (w4<<1)); bank now 2-way (was 4-way).
        u32t* dst = (u32t*)KQX;
        const int gsw = cp >> 2, gin = cp & 3;
        #pragma unroll
        for (int it = 0; it < 8; ++it) {
            int d = dv + it * 4;
            int sw = d & 7;
            int pg = ((gsw ^ sw) ^ (w4 << 1)) * 4 + gin;
            int r0 = w4 * 128 + d;
            dst[(r0 + 0 * 32) * 32 + pg] = pack2(fa[it].x, fb[it].x);
            dst[(r0 + 1 * 32) * 32 + pg] = pack2(fa[it].y, fb[it].y);
            dst[(r0 + 2 * 32) * 32 + pg] = pack2(fa[it].z, fb[it].z);
            dst[(r0 + 3 * 32) * 32 + pg] = pack2(fa[it].w, fb[it].w);
        }
    }

    // ---- prefetch + pack weight A-frags and biases (overlaps barrier) ----
    bf16x8 Af[3][2][2];
    float4 bias4[3][2];
    {
        const float* Wp[3] = {Wk, Wq, Wv};
        const float* bp[3] = {bk, bq, bv};
        #pragma unroll
        for (int p = 0; p < 3; ++p) {
            #pragma unroll
            for (int m0 = 0; m0 < 2; ++m0) {
                #pragma unroll
                for (int ks = 0; ks < 2; ++ks) {
                    const float* src = Wp[p] + (m0 * 16 + l15) * kC + ks * 32 + quad * 8;
                    Af[p][m0][ks] = pack8(*(const float4*)src, *(const float4*)(src + 4));
                }
                bias4[p][m0] = *(const float4*)(bp[p] + m0 * 16 + quad * 4);
            }
        }
    }
    __syncthreads();

    // ---- load B-frags for this wave's 64 n-rows (swizzled granules) ----
    bf16x8 Bf[4][2];
    #pragma unroll
    for (int nt = 0; nt < 4; ++nt) {
        int row = wv * 64 + nt * 16 + l15;
        int gx = (row & 7) ^ ((row >> 7) << 1);
        #pragma unroll
        for (int ks = 0; ks < 2; ++ks)
            Bf[nt][ks] = *(const bf16x8*)&KQX[row * 64 + ((ks * 4 + quad) ^ gx) * 8];
    }

    // ---- projections via MFMA; K,Q -> own LDS rows (bf16); V -> f32 regs ----
    f32x4 Vf[2][4];
    #pragma unroll
    for (int p = 0; p < 3; ++p) {
        #pragma unroll
        for (int m0 = 0; m0 < 2; ++m0) {
            #pragma unroll
            for (int nt = 0; nt < 4; ++nt) {
                f32x4 acc = {0.f, 0.f, 0.f, 0.f};
                acc = __builtin_amdgcn_mfma_f32_16x16x32_bf16(Af[p][m0][0], Bf[nt][0], acc, 0, 0, 0);
                acc = __builtin_amdgcn_mfma_f32_16x16x32_bf16(Af[p][m0][1], Bf[nt][1], acc, 0, 0, 0);
                if (p < 2) {
                    u32t lo = pack2(acc[0] + bias4[p][m0].x, acc[1] + bias4[p][m0].y);
                    u32t hi = pack2(acc[2] + bias4[p][m0].z, acc[3] + bias4[p][m0].w);
                    int row = wv * 64 + nt * 16 + l15;
                    int gx = (row & 7) ^ ((row >> 7) << 1);
                    int g = (p == 0 ? 0 : 4) + m0 * 2 + (quad >> 1);
                    uint2 pr; pr.x = lo; pr.y = hi;
                    *(uint2*)&KQX[row * 64 + ((g ^ gx) * 8) + (quad & 1) * 4] = pr;
                } else {
                    Vf[m0][nt][0] = acc[0] + bias4[2][m0].x;
                    Vf[m0][nt][1] = acc[1] + bias4[2][m0].y;
                    Vf[m0][nt][2] = acc[2] + bias4[2][m0].z;
                    Vf[m0][nt][3] = acc[3] + bias4[2][m0].w;
                }
            }
        }
    }
    // no barrier: scores read only this wave's own rows (in-order DS pipe).

    // ---- scores + softmax (no max-sub) + Abar + Obar, 2 sites/wave ----
    {
        const float kScaleLog2e = 0.25501700249569946f;  // (1/sqrt(32))*log2(e)
        #pragma unroll
        for (int si = 0; si < 2; ++si) {
            int wp = wv * 2 + si;                  // site (w') 0..15
            bf16x8 Ka[2], Qb[2];
            #pragma unroll
            for (int m0 = 0; m0 < 2; ++m0) {
                int rr = wp * 32 + m0 * 16 + l15;
                int gx = (rr & 7) ^ ((rr >> 7) << 1);
                Ka[m0] = *(const bf16x8*)&KQX[rr * 64 + ((quad ^ gx) * 8)];
            }
            #pragma unroll
            for (int n0 = 0; n0 < 2; ++n0) {
                int rr = wp * 32 + n0 * 16 + l15;
                int gx = (rr & 7) ^ ((rr >> 7) << 1);
                Qb[n0] = *(const bf16x8*)&KQX[rr * 64 + (((4 + quad) ^ gx) * 8)];
            }
            f32x4 sc[2][2];
            #pragma unroll
            for (int m0 = 0; m0 < 2; ++m0)
                #pragma unroll
                for (int n0 = 0; n0 < 2; ++n0) {
                    f32x4 z = {0.f, 0.f, 0.f, 0.f};
                    sc[m0][n0] = __builtin_amdgcn_mfma_f32_16x16x32_bf16(Ka[m0], Qb[n0], z, 0, 0, 0);
                }
            // softmax over i per column j = n0*16 + l15
            #pragma unroll
            for (int n0 = 0; n0 < 2; ++n0) {
                float sum = 0.f;
                #pragma unroll
                for (int m0 = 0; m0 < 2; ++m0)
                    #pragma unroll
                    for (int r2 = 0; r2 < 4; ++r2) {
                        float e = exp2f(sc[m0][n0][r2] * kScaleLog2e);
                        sc[m0][n0][r2] = e; sum += e;
                    }
                sum += __shfl_xor(sum, 16);
                sum += __shfl_xor(sum, 32);
                float inv = __builtin_amdgcn_rcpf(sum);
                #pragma unroll
                for (int m0 = 0; m0 < 2; ++m0)
                    #pragma unroll
                    for (int r2 = 0; r2 < 4; ++r2) sc[m0][n0][r2] *= inv;
            }
            // Abar[i] = (1/32) * sum_j a[i,j]  -> AbarS[wp][i]
            #pragma unroll
            for (int m0 = 0; m0 < 2; ++m0)
                #pragma unroll
                for (int r2 = 0; r2 < 4; ++r2) {
                    float v2 = sc[m0][0][r2] + sc[m0][1][r2];
                    v2 += __shfl_xor(v2, 1);
                    v2 += __shfl_xor(v2, 2);
                    v2 += __shfl_xor(v2, 4);
                    v2 += __shfl_xor(v2, 8);
                    if (l15 == 0)
                        AbarS[wp * kD + m0 * 16 + quad * 4 + r2] = v2 * (1.0f / kD);
                }
            // Obar[s] = sum_d V[s,d]*Abar[d] (V f32 C-frags; d = g*16+l15)
            {
                float ab0 = AbarS[wp * kD + l15];
                float ab1 = AbarS[wp * kD + 16 + l15];
                #pragma unroll
                for (int m0 = 0; m0 < 2; ++m0)
                    #pragma unroll
                    for (int r2 = 0; r2 < 4; ++r2) {
                        float v = Vf[m0][2 * si + 0][r2] * ab0
                                + Vf[m0][2 * si + 1][r2] * ab1;
                        v += __shfl_xor(v, 1);
                        v += __shfl_xor(v, 2);
                        v += __shfl_xor(v, 4);
                        v += __shfl_xor(v, 8);
                        if (l15 == 0)
                            ObarS[wp * 36 + m0 * 16 + quad * 4 + r2] = v;
                    }
            }
        }
    }
    __syncthreads();

    // ---- final: out[c] = Xbar + f*(bo + Wo*Obar), coalesced over w ----
    {
        const float fac = factor[0];
        const int wp = t & 15, cl = t >> 4;   // cl 0..31
        const float4* obp = (const float4*)&ObarS[wp * 36];
        float4 ob4[8];
        #pragma unroll
        for (int s4 = 0; s4 < 8; ++s4) ob4[s4] = obp[s4];
        const int odd = cl & 1;
        #pragma unroll
        for (int half = 0; half < 2; ++half) {
            int c = cl + half * 32;
            int cpi = (cl >> 1) + half * 16;
            const int xi = wp * 32 + (cpi ^ wp);
            float xbar = bsel(XbP[0 * 512 + xi], odd)
                       + bsel(XbP[1 * 512 + xi], odd)
                       + bsel(XbP[2 * 512 + xi], odd)
                       + bsel(XbP[3 * 512 + xi], odd);
            xbar *= (1.0f / kD);
            const float4* wrow = (const float4*)(Wo + c * kS);
            float acc = 0.f;
            #pragma unroll
            for (int s4 = 0; s4 < 8; ++s4) {
                float4 w4 = wrow[s4];
                acc += w4.x * ob4[s4].x;
                acc += w4.y * ob4[s4].y;
                acc += w4.z * ob4[s4].z;
                acc += w4.w * ob4[s4].w;
            }
            out[((b * kC + c) * kH + h) * kW + w0 + wp] =
                xbar + fac * (bo[c] + acc);
        }
    }
}

extern "C" void kernel_launch(void* const* d_in, const int* in_sizes, int n_in,
                              void* d_out, int out_size, void* d_ws, size_t ws_size,
                              hipStream_t stream) {
    const float* x      = (const float*)d_in[0];
    const float* Wk     = (const float*)d_in[1];
    const float* bk     = (const float*)d_in[2];
    const float* Wq     = (const float*)d_in[3];
    const float* bq     = (const float*)d_in[4];
    const float* Wv     = (const float*)d_in[5];
    const float* bv     = (const float*)d_in[6];
    const float* Wo     = (const float*)d_in[7];
    const float* bo     = (const float*)d_in[8];
    const float* factor = (const float*)d_in[9];
    float* out = (float*)d_out;

    dim3 grid(kB * kH * (kW / TW));  // 2048 blocks
    attn_fused<<<grid, NT, 0, stream>>>(x, Wk, bk, Wq, bq, Wv, bv, Wo, bo, factor, out);
}

// Round 6
// 418.158 us; speedup vs baseline: 1.0075x; 1.0033x over previous
//
#include <hip/hip_runtime.h>

// R10: the launch_bounds bug round.
//  R9c post-mortem: bank conflicts 4.3M->1.2M with ZERO timing change
//  (not critical path); VGPR stayed 64 despite the asm liveness pin.
//  Root cause found: __launch_bounds__(512, 4) = min 4 blocks/CU x 8
//  waves = 32 waves/CU = 8 waves/SIMD -> hard VGPR cap 512/8 = 64.
//  The ",4" was inherited from the 256-thread era (where it meant 128
//  VGPRs). Real occupancy is LDS-capped at 2 blocks/CU anyway, so the
//  cap bought nothing and forced the RA to recycle the 16 staging-load
//  dests into ~4 batches -> ~4 exposed ~900cy HBM latencies per wave.
//  This is invariant under every swizzle change -> explains the 420us
//  flatline across R0-R9.
//  Fix: __launch_bounds__(512, 2) -> 4 waves/SIMD -> 128 VGPR budget;
//  asm pin + sched_barrier hold all 16 loads in flight, single wait.
//  Everything else identical to R9c (bank fixes retained).
// Math: out = Xbar + f*(bo + Wo*(V*Abar)), Abar = mean_j softmax_i(K^T Q).
// LDS = 65536 + 8192 + 2048 + 2304 = 78,080 B -> 2 blocks/CU.

namespace {
constexpr int kB = 8, kC = 64, kD = 32, kH = 64, kW = 64, kS = 32;
constexpr int kHW = kH * kW;
constexpr int TW = 16, NT = 512;

typedef unsigned short u16t;
typedef unsigned int u32t;
typedef __attribute__((ext_vector_type(8))) short bf16x8;
typedef __attribute__((ext_vector_type(4))) float f32x4;

#if defined(__has_builtin)
#if __has_builtin(__builtin_amdgcn_cvt_pk_bf16_f32)
#define HAS_CVT_PK_BF16 1
#endif
#endif

__device__ __forceinline__ u32t pack2(float lo, float hi) {
#ifdef HAS_CVT_PK_BF16
    typedef __attribute__((ext_vector_type(2))) __bf16 v2bf;
    union { v2bf v; u32t u; } cv;
    cv.v = __builtin_amdgcn_cvt_pk_bf16_f32(lo, hi);
    return cv.u;
#else
    union { u32t i; float f; } a, b;
    a.f = lo; b.f = hi;
    u32t ra = a.i + 0x7FFFu + ((a.i >> 16) & 1u);
    u32t rb = b.i + 0x7FFFu + ((b.i >> 16) & 1u);
    return (ra >> 16) | (rb & 0xFFFF0000u);
#endif
}
__device__ __forceinline__ bf16x8 pack8(const float4 f0, const float4 f1) {
    union { bf16x8 v; u32t u[4]; } r;
    r.u[0] = pack2(f0.x, f0.y); r.u[1] = pack2(f0.z, f0.w);
    r.u[2] = pack2(f1.x, f1.y); r.u[3] = pack2(f1.z, f1.w);
    return r.v;
}
// select bf16 half of a packed pair as f32
__device__ __forceinline__ float bsel(u32t q, int odd) {
    union { u32t i; float f; } v;
    v.i = odd ? (q & 0xFFFF0000u) : (q << 16);
    return v.f;
}
} // namespace

__global__ __launch_bounds__(NT, 2) void attn_fused(
    const float* __restrict__ x,
    const float* __restrict__ Wk, const float* __restrict__ bk,
    const float* __restrict__ Wq, const float* __restrict__ bq,
    const float* __restrict__ Wv, const float* __restrict__ bv,
    const float* __restrict__ Wo, const float* __restrict__ bo,
    const float* __restrict__ factor,
    float* __restrict__ out)
{
    // KQX row (w*32+d) (0..511): 64 ushorts; 16B granule index XOR'd with
    // (row&7) ^ ((row>>7)<<1)  [= (d&7) ^ ((w>>2)<<1)].
    __shared__ __align__(16) u16t KQX[512 * 64];   // 65,536 B
    __shared__ u32t XbP[4 * 512];                  //  8,192 B : [dv][w][cp^w], bf16 pair (c even|odd)
    __shared__ float AbarS[16 * kD];               //  2,048 B : [wp][i]
    __shared__ __align__(16) float ObarS[16 * 36]; //  2,304 B : [wp][s] pad 36

    const int t = threadIdx.x;
    const int lane = t & 63;
    const int wv = t >> 6;        // 0..7
    const int l15 = lane & 15;
    const int quad = lane >> 4;

    // dispatch mapping: R1 verbatim (best measured). 8 (b,h)-siblings of
    // one w-tile round-robin the XCDs; the 4 w-tile siblings of one (b,h)
    // are 8/16/24 dispatch slots apart (co-resident, L2 line merge).
    const int blk = blockIdx.x;                      // 0..2047
    const int bh = (blk & 7) | ((blk >> 5) << 3);    // 0..511
    const int wt = (blk >> 3) & 3;
    const int b = bh >> 6, h = bh & 63, w0 = wt * TW;

    // ---- stage X: 16 loads forced in flight, then consume ----
    // thread map: w4 = t&3 (float4 within 16 w's -> 64B coalesced per (c,d)),
    //             cp = (t>>2)&31 (c-pair), dv = t>>7; d = dv + it*4.
    {
        const float* xb = x + (size_t)(b * kC * kD) * kHW + h * kW + w0;
        const int w4 = t & 3, cp = (t >> 2) & 31, dv = t >> 7;
        const float* p0 = xb + (size_t)((cp * 2) * kD + dv) * kHW + w4 * 4;
        const float* p1 = p0 + (size_t)kD * kHW;
        float4 fa[8], fb[8];
        #pragma unroll
        for (int it = 0; it < 8; ++it) {
            fa[it] = *(const float4*)(p0 + (size_t)(it * 4) * kHW);
            fb[it] = *(const float4*)(p1 + (size_t)(it * 4) * kHW);
        }
        __builtin_amdgcn_sched_barrier(0);   // no motion across this point
        // Liveness pin: read one scalar of each load dest here; the other
        // components are consumed after, so the RA must keep all 16 float4
        // tuples live across this asm -> 16 loads in flight, single wait.
        asm volatile("" ::
            "v"(fa[0].x), "v"(fa[1].x), "v"(fa[2].x), "v"(fa[3].x),
            "v"(fa[4].x), "v"(fa[5].x), "v"(fa[6].x), "v"(fa[7].x),
            "v"(fb[0].x), "v"(fb[1].x), "v"(fb[2].x), "v"(fb[3].x),
            "v"(fb[4].x), "v"(fb[5].x), "v"(fb[6].x), "v"(fb[7].x));

        // Xbar partials over this thread's 8 d's (f32), packed bf16 to LDS
        float4 sA = fa[0], sB = fb[0];
        #pragma unroll
        for (int it = 1; it < 8; ++it) {
            sA.x += fa[it].x; sA.y += fa[it].y; sA.z += fa[it].z; sA.w += fa[it].w;
            sB.x += fb[it].x; sB.y += fb[it].y; sB.z += fb[it].z; sB.w += fb[it].w;
        }
        // in-row index XOR'd with w so epilogue reads spread across banks
        {
            const int wbase = dv * 512 + w4 * 128;
            XbP[wbase + 0 * 32 + (cp ^ (w4 * 4 + 0))] = pack2(sA.x, sB.x);
            XbP[wbase + 1 * 32 + (cp ^ (w4 * 4 + 1))] = pack2(sA.y, sB.y);
            XbP[wbase + 2 * 32 + (cp ^ (w4 * 4 + 2))] = pack2(sA.z, sB.z);
            XbP[wbase + 3 * 32 + (cp ^ (w4 * 4 + 3))] = pack2(sA.w, sB.w);
        }

        // pack + swizzled staging writes; row = (w4*4+e)*32 + d.
        // granule = (gsw ^ (d&7) ^ (w4<<1)); bank 2-way (free).
        u32t* dst = (u32t*)KQX;
        const int gsw = cp >> 2, gin = cp & 3;
        #pragma unroll
        for (int it = 0; it < 8; ++it) {
            int d = dv + it * 4;
            int sw = d & 7;
            int pg = ((gsw ^ sw) ^ (w4 << 1)) * 4 + gin;
            int r0 = w4 * 128 + d;
            dst[(r0 + 0 * 32) * 32 + pg] = pack2(fa[it].x, fb[it].x);
            dst[(r0 + 1 * 32) * 32 + pg] = pack2(fa[it].y, fb[it].y);
            dst[(r0 + 2 * 32) * 32 + pg] = pack2(fa[it].z, fb[it].z);
            dst[(r0 + 3 * 32) * 32 + pg] = pack2(fa[it].w, fb[it].w);
        }
    }

    // ---- prefetch + pack weight A-frags and biases (overlaps barrier) ----
    bf16x8 Af[3][2][2];
    float4 bias4[3][2];
    {
        const float* Wp[3] = {Wk, Wq, Wv};
        const float* bp[3] = {bk, bq, bv};
        #pragma unroll
        for (int p = 0; p < 3; ++p) {
            #pragma unroll
            for (int m0 = 0; m0 < 2; ++m0) {
                #pragma unroll
                for (int ks = 0; ks < 2; ++ks) {
                    const float* src = Wp[p] + (m0 * 16 + l15) * kC + ks * 32 + quad * 8;
                    Af[p][m0][ks] = pack8(*(const float4*)src, *(const float4*)(src + 4));
                }
                bias4[p][m0] = *(const float4*)(bp[p] + m0 * 16 + quad * 4);
            }
        }
    }
    __syncthreads();

    // ---- load B-frags for this wave's 64 n-rows (swizzled granules) ----
    bf16x8 Bf[4][2];
    #pragma unroll
    for (int nt = 0; nt < 4; ++nt) {
        int row = wv * 64 + nt * 16 + l15;
        int gx = (row & 7) ^ ((row >> 7) << 1);
        #pragma unroll
        for (int ks = 0; ks < 2; ++ks)
            Bf[nt][ks] = *(const bf16x8*)&KQX[row * 64 + ((ks * 4 + quad) ^ gx) * 8];
    }

    // ---- projections via MFMA; K,Q -> own LDS rows (bf16); V -> f32 regs ----
    f32x4 Vf[2][4];
    #pragma unroll
    for (int p = 0; p < 3; ++p) {
        #pragma unroll
        for (int m0 = 0; m0 < 2; ++m0) {
            #pragma unroll
            for (int nt = 0; nt < 4; ++nt) {
                f32x4 acc = {0.f, 0.f, 0.f, 0.f};
                acc = __builtin_amdgcn_mfma_f32_16x16x32_bf16(Af[p][m0][0], Bf[nt][0], acc, 0, 0, 0);
                acc = __builtin_amdgcn_mfma_f32_16x16x32_bf16(Af[p][m0][1], Bf[nt][1], acc, 0, 0, 0);
                if (p < 2) {
                    u32t lo = pack2(acc[0] + bias4[p][m0].x, acc[1] + bias4[p][m0].y);
                    u32t hi = pack2(acc[2] + bias4[p][m0].z, acc[3] + bias4[p][m0].w);
                    int row = wv * 64 + nt * 16 + l15;
                    int gx = (row & 7) ^ ((row >> 7) << 1);
                    int g = (p == 0 ? 0 : 4) + m0 * 2 + (quad >> 1);
                    uint2 pr; pr.x = lo; pr.y = hi;
                    *(uint2*)&KQX[row * 64 + ((g ^ gx) * 8) + (quad & 1) * 4] = pr;
                } else {
                    Vf[m0][nt][0] = acc[0] + bias4[2][m0].x;
                    Vf[m0][nt][1] = acc[1] + bias4[2][m0].y;
                    Vf[m0][nt][2] = acc[2] + bias4[2][m0].z;
                    Vf[m0][nt][3] = acc[3] + bias4[2][m0].w;
                }
            }
        }
    }
    // no barrier: scores read only this wave's own rows (in-order DS pipe).

    // ---- scores + softmax (no max-sub) + Abar + Obar, 2 sites/wave ----
    {
        const float kScaleLog2e = 0.25501700249569946f;  // (1/sqrt(32))*log2(e)
        #pragma unroll
        for (int si = 0; si < 2; ++si) {
            int wp = wv * 2 + si;                  // site (w') 0..15
            bf16x8 Ka[2], Qb[2];
            #pragma unroll
            for (int m0 = 0; m0 < 2; ++m0) {
                int rr = wp * 32 + m0 * 16 + l15;
                int gx = (rr & 7) ^ ((rr >> 7) << 1);
                Ka[m0] = *(const bf16x8*)&KQX[rr * 64 + ((quad ^ gx) * 8)];
            }
            #pragma unroll
            for (int n0 = 0; n0 < 2; ++n0) {
                int rr = wp * 32 + n0 * 16 + l15;
                int gx = (rr & 7) ^ ((rr >> 7) << 1);
                Qb[n0] = *(const bf16x8*)&KQX[rr * 64 + (((4 + quad) ^ gx) * 8)];
            }
            f32x4 sc[2][2];
            #pragma unroll
            for (int m0 = 0; m0 < 2; ++m0)
                #pragma unroll
                for (int n0 = 0; n0 < 2; ++n0) {
                    f32x4 z = {0.f, 0.f, 0.f, 0.f};
                    sc[m0][n0] = __builtin_amdgcn_mfma_f32_16x16x32_bf16(Ka[m0], Qb[n0], z, 0, 0, 0);
                }
            // softmax over i per column j = n0*16 + l15
            #pragma unroll
            for (int n0 = 0; n0 < 2; ++n0) {
                float sum = 0.f;
                #pragma unroll
                for (int m0 = 0; m0 < 2; ++m0)
                    #pragma unroll
                    for (int r2 = 0; r2 < 4; ++r2) {
                        float e = exp2f(sc[m0][n0][r2] * kScaleLog2e);
                        sc[m0][n0][r2] = e; sum += e;
                    }
                sum += __shfl_xor(sum, 16);
                sum += __shfl_xor(sum, 32);
                float inv = __builtin_amdgcn_rcpf(sum);
                #pragma unroll
                for (int m0 = 0; m0 < 2; ++m0)
                    #pragma unroll
                    for (int r2 = 0; r2 < 4; ++r2) sc[m0][n0][r2] *= inv;
            }
            // Abar[i] = (1/32) * sum_j a[i,j]  -> AbarS[wp][i]
            #pragma unroll
            for (int m0 = 0; m0 < 2; ++m0)
                #pragma unroll
                for (int r2 = 0; r2 < 4; ++r2) {
                    float v2 = sc[m0][0][r2] + sc[m0][1][r2];
                    v2 += __shfl_xor(v2, 1);
                    v2 += __shfl_xor(v2, 2);
                    v2 += __shfl_xor(v2, 4);
                    v2 += __shfl_xor(v2, 8);
                    if (l15 == 0)
                        AbarS[wp * kD + m0 * 16 + quad * 4 + r2] = v2 * (1.0f / kD);
                }
            // Obar[s] = sum_d V[s,d]*Abar[d] (V f32 C-frags; d = g*16+l15)
            {
                float ab0 = AbarS[wp * kD + l15];
                float ab1 = AbarS[wp * kD + 16 + l15];
                #pragma unroll
                for (int m0 = 0; m0 < 2; ++m0)
                    #pragma unroll
                    for (int r2 = 0; r2 < 4; ++r2) {
                        float v = Vf[m0][2 * si + 0][r2] * ab0
                                + Vf[m0][2 * si + 1][r2] * ab1;
                        v += __shfl_xor(v, 1);
                        v += __shfl_xor(v, 2);
                        v += __shfl_xor(v, 4);
                        v += __shfl_xor(v, 8);
                        if (l15 == 0)
                            ObarS[wp * 36 + m0 * 16 + quad * 4 + r2] = v;
                    }
            }
        }
    }
    __syncthreads();

    // ---- final: out[c] = Xbar + f*(bo + Wo*Obar), coalesced over w ----
    {
        const float fac = factor[0];
        const int wp = t & 15, cl = t >> 4;   // cl 0..31
        const float4* obp = (const float4*)&ObarS[wp * 36];
        float4 ob4[8];
        #pragma unroll
        for (int s4 = 0; s4 < 8; ++s4) ob4[s4] = obp[s4];
        const int odd = cl & 1;
        #pragma unroll
        for (int half = 0; half < 2; ++half) {
            int c = cl + half * 32;
            int cpi = (cl >> 1) + half * 16;
            const int xi = wp * 32 + (cpi ^ wp);
            float xbar = bsel(XbP[0 * 512 + xi], odd)
                       + bsel(XbP[1 * 512 + xi], odd)
                       + bsel(XbP[2 * 512 + xi], odd)
                       + bsel(XbP[3 * 512 + xi], odd);
            xbar *= (1.0f / kD);
            const float4* wrow = (const float4*)(Wo + c * kS);
            float acc = 0.f;
            #pragma unroll
            for (int s4 = 0; s4 < 8; ++s4) {
                float4 w4 = wrow[s4];
                acc += w4.x * ob4[s4].x;
                acc += w4.y * ob4[s4].y;
                acc += w4.z * ob4[s4].z;
                acc += w4.w * ob4[s4].w;
            }
            out[((b * kC + c) * kH + h) * kW + w0 + wp] =
                xbar + fac * (bo[c] + acc);
        }
    }
}

extern "C" void kernel_launch(void* const* d_in, const int* in_sizes, int n_in,
                              void* d_out, int out_size, void* d_ws, size_t ws_size,
                              hipStream_t stream) {
    const float* x      = (const float*)d_in[0];
    const float* Wk     = (const float*)d_in[1];
    const float* bk     = (const float*)d_in[2];
    const float* Wq     = (const float*)d_in[3];
    const float* bq     = (const float*)d_in[4];
    const float* Wv     = (const float*)d_in[5];
    const float* bv     = (const float*)d_in[6];
    const float* Wo     = (const float*)d_in[7];
    const float* bo     = (const float*)d_in[8];
    const float* factor = (const float*)d_in[9];
    float* out = (float*)d_out;

    dim3 grid(kB * kH * (kW / TW));  // 2048 blocks
    attn_fused<<<grid, NT, 0, stream>>>(x, Wk, bk, Wq, bq, Wv, bv, Wo, bo, factor, out);
}